// Round 1
// baseline (168.663 us; speedup 1.0000x reference)
//
#include <hip/hip_runtime.h>
#include <math.h>

// CRF log-likelihood, B=2048, T=80, L=128 — v9: wave-autonomous recurrence.
//
// v8 was latency-bound (MfmaUtil 12.6%, VALUBusy 35%, HBM 10%): every serial
// step paid an LDS round-trip + __syncthreads across 8 waves. v9 relabels the
// state space so ONE wave owns the whole 128-state chain in registers:
//   D-layout (tile mt, reg r)  -> state 32q + 4mt + r   (q = lane quad)
//   B-layout (tile kk, elem j) -> state 32q + 8kk + j
// Both layouts assign quad q the SAME state set [32q, 32q+32), so next step's
// B-fragment = pack of the lane's own D-output registers. No LDS, no barrier,
// no cross-lane movement in the main loop. Block = 2 waves (fwd + bwd of the
// same 4 rows, meet-in-the-middle), grid = 512 -> 1024 independent waves
// (1/SIMD); per-step cost = max(32 MFMA pipe cycles, co-issued VALU).
// A-fragments hold the full exp(trans) (fwd: E^T, bwd: E) = 128 VGPR/wave.
// Renorm every 4 steps via in-wave shfl_xor max (masks 4/8/16/32), delayed
// apply. Combine: bwd does one emission-free MFMA pass (u = E v_40), hands u
// to fwd via 2KB LDS, fwd dots with a_39 (replica sum / 4).

#define CRF_B 2048
#define CRF_T 80
#define CRF_L 128

typedef __attribute__((ext_vector_type(8))) short bf16x8_t;
typedef __attribute__((ext_vector_type(4))) float f32x4_t;

__device__ __forceinline__ int pack_bf16_trunc(float lo, float hi) {
    return (int)((__float_as_uint(lo) >> 16) | (__float_as_uint(hi) & 0xFFFF0000u));
}
__device__ __forceinline__ unsigned short bft(float f) {
    return (unsigned short)(__float_as_uint(f) >> 16);
}

__global__ __launch_bounds__(128, 1) void crf_v9_kernel(
    const float* __restrict__ x,           // [B,T,L]
    const float* __restrict__ trans,       // [L,L]
    const float* __restrict__ start_trans, // [L]
    const float* __restrict__ end_trans,   // [L]
    const int*   __restrict__ y,           // [B,T]
    float* __restrict__ out)               // [B]
{
    const int tid  = threadIdx.x;
    const int w    = tid >> 6;          // 0 = forward wave, 1 = backward wave
    const int lane = tid & 63;
    const int q    = lane >> 4;         // quad: owns states [32q, 32q+32)
    const int a    = lane & 15;         // MFMA n-column; real batch row = a & 3
    const int row0 = blockIdx.x * 4;
    const int brow = row0 + (a & 3);

    __shared__ __attribute__((aligned(16))) float u_lds[4][132];
    __shared__ float crunB_lds[4];
    __shared__ float numb[4];

    // ---------------- numerator: wave w -> rows 2w, 2w+1 ----------------
    #pragma unroll
    for (int rr = 0; rr < 2; ++rr) {
        const int bb = row0 + 2 * w + rr;
        const int* yb = y + bb * CRF_T;
        const float* xbn = x + (size_t)bb * CRF_T * CRF_L;
        float p = 0.f;
        for (int t = lane; t < CRF_T; t += 64) {
            const int yt = yb[t];
            p += xbn[t * CRF_L + yt];
            p += (t + 1 < CRF_T) ? trans[yt * CRF_L + yb[t + 1]] : end_trans[yt];
            if (t == 0) p += start_trans[yt];
        }
        #pragma unroll
        for (int off = 1; off <= 32; off <<= 1) p += __shfl_xor(p, off);
        if (lane == 0) numb[2 * w + rr] = p;
    }

    // ---------------- A-fragments: full exp(trans), relabeled ----------------
    // A[m=a][k=8q+j] of tile (mt,kk) = Ê[in_state -> out_state] with
    //   out_state = 32*(a>>2) + 4*mt + (a&3),  in_state = 32*q + 8*kk + j.
    // fwd: Ê = exp(trans[in][out]);  bwd: Ê = exp(trans[out][in]).
    bf16x8_t Afr[8][4];
    {
        const int out_lo = 32 * (a >> 2) + (a & 3);
        const int in_lo  = 32 * q;
        const int so = w ? CRF_L : 1;   // stride of out_s in trans
        const int si = w ? 1 : CRF_L;   // stride of in_s  in trans
        #pragma unroll
        for (int mt = 0; mt < 8; ++mt) {
            const int ob = (out_lo + 4 * mt) * so;
            #pragma unroll
            for (int kk = 0; kk < 4; ++kk) {
                union { bf16x8_t v; unsigned short s[8]; } u;
                #pragma unroll
                for (int j = 0; j < 8; ++j) {
                    const int in_s = in_lo + 8 * kk + j;
                    u.s[j] = bft(__expf(trans[ob + in_s * si]));
                }
                Afr[mt][kk] = u.v;
            }
        }
    }

    const float* xr = x + (size_t)brow * CRF_T * CRF_L;
    int tcur = w ? 78 : 1;
    const int tstep = w ? -1 : 1;

    // ---------------- init: a_0 (fwd) / v_79 (bwd), pack to B-frags ----------------
    float P[8][4];
    bf16x8_t Bfr[4];
    {
        const float* bias = w ? end_trans : start_trans;
        const float* xp = xr + (size_t)(w ? 79 : 0) * CRF_L + 32 * q;
        const float* bp = bias + 32 * q;
        #pragma unroll
        for (int mt = 0; mt < 8; ++mt) {
            const f32x4_t bv = *(const f32x4_t*)&bp[4 * mt];
            const f32x4_t xv = *(const f32x4_t*)&xp[4 * mt];
            #pragma unroll
            for (int r = 0; r < 4; ++r) P[mt][r] = __expf(bv[r] + xv[r]);
        }
        #pragma unroll
        for (int kk = 0; kk < 4; ++kk) {
            union { bf16x8_t v; int wd[4]; } u;
            u.wd[0] = pack_bf16_trunc(P[2 * kk][0],     P[2 * kk][1]);
            u.wd[1] = pack_bf16_trunc(P[2 * kk][2],     P[2 * kk][3]);
            u.wd[2] = pack_bf16_trunc(P[2 * kk + 1][0], P[2 * kk + 1][1]);
            u.wd[3] = pack_bf16_trunc(P[2 * kk + 1][2], P[2 * kk + 1][3]);
            Bfr[kk] = u.v;
        }
    }

    // current emissions
    f32x4_t xc[8], xn[8];
    {
        const float* xp = xr + (size_t)tcur * CRF_L + 32 * q;
        #pragma unroll
        for (int mt = 0; mt < 8; ++mt) xc[mt] = *(const f32x4_t*)&xp[4 * mt];
    }

    float crun = 0.f, inv = 1.f, Mv = 1.f;

    // One recurrence step. MEASURE/APPLY/LAST are literal 0/1 (dead-code
    // eliminated). All array indices compile-time constant (no scratch).
#define CRF_STEP(MEASURE, APPLY, LAST) do {                                     \
        if (!(LAST)) {                                                          \
            const float* xp_ = xr + (size_t)(tcur + tstep) * CRF_L + 32 * q;    \
            _Pragma("unroll")                                                   \
            for (int mt = 0; mt < 8; ++mt) xn[mt] = *(const f32x4_t*)&xp_[4*mt];\
        }                                                                       \
        if (APPLY) { crun += __logf(Mv); inv = __builtin_amdgcn_rcpf(Mv); }     \
        float e_[8][4];                                                         \
        _Pragma("unroll")                                                       \
        for (int mt = 0; mt < 8; ++mt)                                          \
            _Pragma("unroll")                                                   \
            for (int r = 0; r < 4; ++r) {                                       \
                float v_ = __expf(xc[mt][r]);                                   \
                if (APPLY) v_ *= inv;                                           \
                e_[mt][r] = v_;                                                 \
            }                                                                   \
        _Pragma("unroll")                                                       \
        for (int mt = 0; mt < 8; ++mt) {                                        \
            f32x4_t a_ = {0.f, 0.f, 0.f, 0.f};                                  \
            _Pragma("unroll")                                                   \
            for (int kk = 0; kk < 4; ++kk)                                      \
                a_ = __builtin_amdgcn_mfma_f32_16x16x32_bf16(Afr[mt][kk],       \
                                                             Bfr[kk], a_,      \
                                                             0, 0, 0);         \
            _Pragma("unroll")                                                   \
            for (int r = 0; r < 4; ++r) P[mt][r] = a_[r] * e_[mt][r];           \
        }                                                                       \
        _Pragma("unroll")                                                       \
        for (int kk = 0; kk < 4; ++kk) {                                        \
            union { bf16x8_t v; int wd[4]; } u_;                                \
            u_.wd[0] = pack_bf16_trunc(P[2 * kk][0],     P[2 * kk][1]);         \
            u_.wd[1] = pack_bf16_trunc(P[2 * kk][2],     P[2 * kk][3]);         \
            u_.wd[2] = pack_bf16_trunc(P[2 * kk + 1][0], P[2 * kk + 1][1]);     \
            u_.wd[3] = pack_bf16_trunc(P[2 * kk + 1][2], P[2 * kk + 1][3]);     \
            Bfr[kk] = u_.v;                                                     \
        }                                                                       \
        if (MEASURE) {                                                          \
            float g_ = P[0][0];                                                 \
            _Pragma("unroll")                                                   \
            for (int mt = 0; mt < 8; ++mt)                                      \
                _Pragma("unroll")                                               \
                for (int r = 0; r < 4; ++r) g_ = fmaxf(g_, P[mt][r]);           \
            g_ = fmaxf(g_, __shfl_xor(g_, 4));                                  \
            g_ = fmaxf(g_, __shfl_xor(g_, 8));                                  \
            g_ = fmaxf(g_, __shfl_xor(g_, 16));                                 \
            g_ = fmaxf(g_, __shfl_xor(g_, 32));                                 \
            Mv = g_;                                                            \
        }                                                                       \
        if (!(LAST)) {                                                          \
            _Pragma("unroll")                                                   \
            for (int mt = 0; mt < 8; ++mt) xc[mt] = xn[mt];                     \
            tcur += tstep;                                                      \
        }                                                                       \
    } while (0)

    // ---------------- 39 steps: fwd t=1..39, bwd t=78..40 ----------------
    // cadence: measure at k = 4m+3 (3..35), apply at k = 4m+4 (4..36)
    for (int k4 = 0; k4 < 9; ++k4) {
        CRF_STEP(0, 0, 0);   // k = 4m+1
        CRF_STEP(0, 0, 0);   // k = 4m+2
        CRF_STEP(1, 0, 0);   // k = 4m+3: measure
        CRF_STEP(0, 1, 0);   // k = 4m+4: apply
    }
    CRF_STEP(0, 0, 0);       // k = 37
    CRF_STEP(0, 0, 0);       // k = 38
    CRF_STEP(0, 0, 1);       // k = 39 (no prefetch)
#undef CRF_STEP

    // ---------------- combine: Z = a_39 . (E v_40) ----------------
    if (w == 1) {
        // u = E v_40 : one emission-free pass; Afr already holds E in layout
        #pragma unroll
        for (int mt = 0; mt < 8; ++mt) {
            f32x4_t a_ = {0.f, 0.f, 0.f, 0.f};
            #pragma unroll
            for (int kk = 0; kk < 4; ++kk)
                a_ = __builtin_amdgcn_mfma_f32_16x16x32_bf16(Afr[mt][kk],
                                                             Bfr[kk], a_,
                                                             0, 0, 0);
            if (a < 4)  // replica 0 lanes write u for their 4 rows
                *(f32x4_t*)&u_lds[a][32 * q + 4 * mt] = a_;
        }
        if (a < 4 && q == 0) crunB_lds[a] = crun;
    }
    __syncthreads();
    if (w == 0) {
        float s = 0.f;
        #pragma unroll
        for (int mt = 0; mt < 8; ++mt) {
            const f32x4_t uv = *(const f32x4_t*)&u_lds[a & 3][32 * q + 4 * mt];
            #pragma unroll
            for (int r = 0; r < 4; ++r) s += P[mt][r] * uv[r];
        }
        // sum over the 16 lanes sharing this row (4 replicas x 4 quads = 4*Z)
        s += __shfl_xor(s, 4);
        s += __shfl_xor(s, 8);
        s += __shfl_xor(s, 16);
        s += __shfl_xor(s, 32);
        if (a < 4 && q == 0)
            out[row0 + a] = numb[a] - (crun + crunB_lds[a] + __logf(s * 0.25f));
    }
}

extern "C" void kernel_launch(void* const* d_in, const int* in_sizes, int n_in,
                              void* d_out, int out_size, void* d_ws, size_t ws_size,
                              hipStream_t stream) {
    const float* x     = (const float*)d_in[0];
    const float* trans = (const float*)d_in[1];
    const float* st    = (const float*)d_in[2];
    const float* et    = (const float*)d_in[3];
    const int*   y     = (const int*)d_in[4];
    float* out = (float*)d_out;

    crf_v9_kernel<<<CRF_B / 4, 128, 0, stream>>>(x, trans, st, et, y, out);
}